// Round 8
// baseline (150.827 us; speedup 1.0000x reference)
//
#include <hip/hip_runtime.h>

#define NB 8
#define NS 2048
#define ND 768
#define ND4 192      // ND/4
#define SC 128       // S-chunks for the v column-sum
#define RPC 16       // rows per chunk = NS/SC

typedef float f4 __attribute__((ext_vector_type(4)));

// ============ K1: v partial sums + last-8-blocks-per-batch do reduce+matvec ============
// grid (SC, NB), block 192. Deterministic: which blocks run BC varies, but BC's
// arithmetic (reduction order c=0..127, fixed row ownership) is fixed -> same output.
__global__ __launch_bounds__(192) void vpart_bc_kernel(
    const float* __restrict__ v, const float* __restrict__ fcw,
    const float* __restrict__ fcb, float* __restrict__ part,
    float* __restrict__ hvec, int* __restrict__ cnt) {
    const int c = blockIdx.x, b = blockIdx.y, t = threadIdx.x;
    __shared__ float lds_vs[ND];
    __shared__ int ticket_s;

    // ---- A: sum rows [c*16, c*16+16) of v[b] -> part[c][b][:]
    {
        const f4* v4 = (const f4*)v + ((size_t)(b * NS + c * RPC)) * ND4 + t;
        f4 acc = (f4)(0.f);
#pragma unroll
        for (int i = 0; i < RPC; ++i) acc += v4[(size_t)i * ND4];
        ((f4*)part)[((size_t)c * NB + b) * ND4 + t] = acc;
    }
    __threadfence();
    __syncthreads();
    if (t == 0)
        ticket_s = __hip_atomic_fetch_add(&cnt[b], 1, __ATOMIC_RELEASE,
                                          __HIP_MEMORY_SCOPE_AGENT);
    __syncthreads();
    const int ticket = ticket_s;
    if (ticket < SC - 8) return;          // not elected
    const int slab = ticket - (SC - 8);   // 0..7

    // wait until all 128 partials of batch b are visible (short: we were among the last)
    if (t == 0)
        while (__hip_atomic_load(&cnt[b], __ATOMIC_ACQUIRE,
                                 __HIP_MEMORY_SCOPE_AGENT) < SC) {}
    __syncthreads();

    // ---- B: reduce part[:,b,:] -> lds_vs (192 threads, one f4 column each)
    {
        const f4* p4 = (const f4*)part + (size_t)b * ND4 + t;
        f4 acc = (f4)(0.f);
#pragma unroll 8
        for (int cc = 0; cc < SC; ++cc) acc += p4[(size_t)cc * (NB * ND4)];
        ((f4*)lds_vs)[t] = acc;
    }
    __syncthreads();

    // ---- C: 96 fc_w rows for this slab; 3 waves x 32 rows, 4 rows in flight
    // per wave via 16-lane groups.
    {
        const int w = t >> 6, l = t & 63;
        const int g = l >> 4, li = l & 15;
#pragma unroll
        for (int it = 0; it < 8; ++it) {
            const int d = slab * 96 + w * 32 + it * 4 + g;
            const f4* wrow = (const f4*)(fcw + (size_t)d * ND);
            float s = 0.f;
#pragma unroll
            for (int j = 0; j < 12; ++j) {
                const int e4 = li + j * 16;
                const f4 wv = wrow[e4];
                const f4 vs = ((const f4*)lds_vs)[e4];
                s += wv.x * vs.x + wv.y * vs.y + wv.z * vs.z + wv.w * vs.w;
            }
            s += __shfl_xor(s, 1, 64); s += __shfl_xor(s, 2, 64);
            s += __shfl_xor(s, 4, 64); s += __shfl_xor(s, 8, 64);
            if (li == 0) hvec[b * ND + d] = s + fcb[d];
        }
    }
}

// ============ K2: out = LayerNorm(q + hvec[b]) * g + beta ============
// grid 1024, block 256; each wave owns 4 rows held in registers; NT stores.
__global__ __launch_bounds__(256) void ln_kernel(const float* __restrict__ q,
                                                 const float* __restrict__ hvec,
                                                 const float* __restrict__ lng,
                                                 const float* __restrict__ lnb,
                                                 float* __restrict__ out) {
    const int w = threadIdx.x >> 6, l = threadIdx.x & 63;
    const int r0 = blockIdx.x * 16 + w * 4;    // wave's rows r0..r0+3
    const int b = r0 >> 11;

    const f4* qb = (const f4*)q + (size_t)r0 * ND4;
    f4 qreg[12];
#pragma unroll
    for (int r = 0; r < 4; ++r)
#pragma unroll
        for (int k = 0; k < 3; ++k)
            qreg[r * 3 + k] = qb[(size_t)r * ND4 + l + k * 64];

    const f4* h4 = (const f4*)hvec + (size_t)b * ND4;
    f4 h[3];
#pragma unroll
    for (int k = 0; k < 3; ++k) h[k] = h4[l + k * 64];

    float s[4], sq[4];
#pragma unroll
    for (int r = 0; r < 4; ++r) {
        s[r] = 0.f; sq[r] = 0.f;
#pragma unroll
        for (int k = 0; k < 3; ++k) {
            const f4 x = qreg[r * 3 + k] + h[k];
            s[r]  += x.x + x.y + x.z + x.w;
            sq[r] += x.x * x.x + x.y * x.y + x.z * x.z + x.w * x.w;
        }
    }
#pragma unroll
    for (int off = 32; off >= 1; off >>= 1)
#pragma unroll
        for (int r = 0; r < 4; ++r) {
            s[r]  += __shfl_xor(s[r],  off, 64);
            sq[r] += __shfl_xor(sq[r], off, 64);
        }
    const float inv = 1.0f / (float)ND;
    float mean[4], rstd[4];
#pragma unroll
    for (int r = 0; r < 4; ++r) {
        mean[r] = s[r] * inv;
        rstd[r] = rsqrtf(sq[r] * inv - mean[r] * mean[r] + 1e-5f);
    }
    f4* o4 = (f4*)out + (size_t)r0 * ND4;
#pragma unroll
    for (int k = 0; k < 3; ++k) {
        const int e4 = l + k * 64;
        const f4 gv = ((const f4*)lng)[e4];
        const f4 bv = ((const f4*)lnb)[e4];
#pragma unroll
        for (int r = 0; r < 4; ++r) {
            const f4 x = qreg[r * 3 + k] + h[k];
            f4 ov;
            ov.x = (x.x - mean[r]) * rstd[r] * gv.x + bv.x;
            ov.y = (x.y - mean[r]) * rstd[r] * gv.y + bv.y;
            ov.z = (x.z - mean[r]) * rstd[r] * gv.z + bv.z;
            ov.w = (x.w - mean[r]) * rstd[r] * gv.w + bv.w;
            __builtin_nontemporal_store(ov, o4 + (size_t)r * ND4 + e4);
        }
    }
}

extern "C" void kernel_launch(void* const* d_in, const int* in_sizes, int n_in,
                              void* d_out, int out_size, void* d_ws, size_t ws_size,
                              hipStream_t stream) {
    // setup_inputs order: q, k, v, mask, fc_w, fc_b, ln_g, ln_b, index, typeAdd_Del
    const float* q   = (const float*)d_in[0];
    const float* v   = (const float*)d_in[2];
    const float* fcw = (const float*)d_in[4];
    const float* fcb = (const float*)d_in[5];
    const float* lng = (const float*)d_in[6];
    const float* lnb = (const float*)d_in[7];
    float* out = (float*)d_out;

    float* part = (float*)d_ws;                 // SC*NB*ND floats = 3 MB
    float* hvec = part + (size_t)SC * NB * ND;  // NB*ND floats
    int*   cnt  = (int*)(hvec + NB * ND);       // NB ints

    (void)hipMemsetAsync(cnt, 0, NB * sizeof(int), stream);
    vpart_bc_kernel<<<dim3(SC, NB), 192, 0, stream>>>(v, fcw, fcb, part, hvec, cnt);
    ln_kernel<<<(NB * NS) / 16, 256, 0, stream>>>(q, hvec, lng, lnb, out);
}

// Round 9
// 43.118 us; speedup vs baseline: 3.4980x; 3.4980x over previous
//
#include <hip/hip_runtime.h>

#define NB 8
#define NS 2048
#define ND 768
#define ND4 192      // ND/4
#define SC 128       // S-chunks for the v column-sum
#define RPC 16       // rows per chunk = NS/SC

typedef float f4 __attribute__((ext_vector_type(4)));

// ============ K1: partial column-sums of v over S ============
// grid (SC, NB), block 192; block (c,b) sums rows [c*16, c*16+16) of v[b].
__global__ __launch_bounds__(192) void vpart_kernel(const float* __restrict__ v,
                                                    float* __restrict__ part) {
    const int c = blockIdx.x, b = blockIdx.y, t = threadIdx.x;
    const f4* v4 = (const f4*)v + ((size_t)(b * NS + c * RPC)) * ND4 + t;
    f4 acc = (f4)(0.f);
#pragma unroll
    for (int i = 0; i < RPC; ++i) acc += v4[(size_t)i * ND4];
    ((f4*)part)[((size_t)c * NB + b) * ND4 + t] = acc;
}

// ============ K2: fused reduce + matvec ============
// 64 blocks x 256: block (slab = bx>>3, b = bx&7) reduces part[:,b,:] into LDS,
// then computes hvec[b][slab*96 .. slab*96+96) with 4 rows in flight per wave
// via 16-lane groups (short shuffle chains).
__global__ __launch_bounds__(256) void bc_kernel(const float* __restrict__ part,
                                                 const float* __restrict__ fcw,
                                                 const float* __restrict__ fcb,
                                                 float* __restrict__ hvec) {
    const int slab = blockIdx.x >> 3, b = blockIdx.x & 7, t = threadIdx.x;
    __shared__ float lds_vs[ND];

    if (t < ND4) {
        const f4* p4 = (const f4*)part + (size_t)b * ND4 + t;
        f4 acc = (f4)(0.f);
#pragma unroll 8
        for (int c = 0; c < SC; ++c) acc += p4[(size_t)c * (NB * ND4)];
        ((f4*)lds_vs)[t] = acc;
    }
    __syncthreads();

    const int w = t >> 6, l = t & 63;
    const int g = l >> 4, li = l & 15;
#pragma unroll
    for (int it = 0; it < 6; ++it) {
        const int d = slab * 96 + w * 24 + it * 4 + g;
        const f4* wrow = (const f4*)(fcw + (size_t)d * ND);
        float s = 0.f;
#pragma unroll
        for (int j = 0; j < 12; ++j) {
            const int e4 = li + j * 16;
            const f4 wv = wrow[e4];
            const f4 vs = ((const f4*)lds_vs)[e4];
            s += wv.x * vs.x + wv.y * vs.y + wv.z * vs.z + wv.w * vs.w;
        }
        s += __shfl_xor(s, 1, 64); s += __shfl_xor(s, 2, 64);
        s += __shfl_xor(s, 4, 64); s += __shfl_xor(s, 8, 64);
        if (li == 0) hvec[b * ND + d] = s + fcb[d];
    }
}

// ============ K3: out = LayerNorm(q + hvec[b]) * g + beta ============
// 1024 blocks x 256; each wave owns 4 rows held in registers; NT stores.
__global__ __launch_bounds__(256) void ln_kernel(const float* __restrict__ q,
                                                 const float* __restrict__ hvec,
                                                 const float* __restrict__ lng,
                                                 const float* __restrict__ lnb,
                                                 float* __restrict__ out) {
    const int w = threadIdx.x >> 6, l = threadIdx.x & 63;
    const int r0 = blockIdx.x * 16 + w * 4;    // wave's rows r0..r0+3
    const int b = r0 >> 11;

    const f4* qb = (const f4*)q + (size_t)r0 * ND4;
    f4 qreg[12];
#pragma unroll
    for (int r = 0; r < 4; ++r)
#pragma unroll
        for (int k = 0; k < 3; ++k)
            qreg[r * 3 + k] = qb[(size_t)r * ND4 + l + k * 64];

    const f4* h4 = (const f4*)hvec + (size_t)b * ND4;
    f4 h[3];
#pragma unroll
    for (int k = 0; k < 3; ++k) h[k] = h4[l + k * 64];

    float s[4], sq[4];
#pragma unroll
    for (int r = 0; r < 4; ++r) {
        s[r] = 0.f; sq[r] = 0.f;
#pragma unroll
        for (int k = 0; k < 3; ++k) {
            const f4 x = qreg[r * 3 + k] + h[k];
            s[r]  += x.x + x.y + x.z + x.w;
            sq[r] += x.x * x.x + x.y * x.y + x.z * x.z + x.w * x.w;
        }
    }
#pragma unroll
    for (int off = 32; off >= 1; off >>= 1)
#pragma unroll
        for (int r = 0; r < 4; ++r) {
            s[r]  += __shfl_xor(s[r],  off, 64);
            sq[r] += __shfl_xor(sq[r], off, 64);
        }
    const float inv = 1.0f / (float)ND;
    float mean[4], rstd[4];
#pragma unroll
    for (int r = 0; r < 4; ++r) {
        mean[r] = s[r] * inv;
        rstd[r] = rsqrtf(sq[r] * inv - mean[r] * mean[r] + 1e-5f);
    }
    f4* o4 = (f4*)out + (size_t)r0 * ND4;
#pragma unroll
    for (int k = 0; k < 3; ++k) {
        const int e4 = l + k * 64;
        const f4 gv = ((const f4*)lng)[e4];
        const f4 bv = ((const f4*)lnb)[e4];
#pragma unroll
        for (int r = 0; r < 4; ++r) {
            const f4 x = qreg[r * 3 + k] + h[k];
            f4 ov;
            ov.x = (x.x - mean[r]) * rstd[r] * gv.x + bv.x;
            ov.y = (x.y - mean[r]) * rstd[r] * gv.y + bv.y;
            ov.z = (x.z - mean[r]) * rstd[r] * gv.z + bv.z;
            ov.w = (x.w - mean[r]) * rstd[r] * gv.w + bv.w;
            __builtin_nontemporal_store(ov, o4 + (size_t)r * ND4 + e4);
        }
    }
}

extern "C" void kernel_launch(void* const* d_in, const int* in_sizes, int n_in,
                              void* d_out, int out_size, void* d_ws, size_t ws_size,
                              hipStream_t stream) {
    // setup_inputs order: q, k, v, mask, fc_w, fc_b, ln_g, ln_b, index, typeAdd_Del
    const float* q   = (const float*)d_in[0];
    const float* v   = (const float*)d_in[2];
    const float* fcw = (const float*)d_in[4];
    const float* fcb = (const float*)d_in[5];
    const float* lng = (const float*)d_in[6];
    const float* lnb = (const float*)d_in[7];
    float* out = (float*)d_out;

    float* part = (float*)d_ws;                 // SC*NB*ND floats = 3 MB
    float* hvec = part + (size_t)SC * NB * ND;  // NB*ND floats

    vpart_kernel<<<dim3(SC, NB), 192, 0, stream>>>(v, part);
    bc_kernel<<<64, 256, 0, stream>>>(part, fcw, fcb, hvec);
    ln_kernel<<<(NB * NS) / 16, 256, 0, stream>>>(q, hvec, lng, lnb, out);
}